// Round 1
// baseline (257.614 us; speedup 1.0000x reference)
//
#include <hip/hip_runtime.h>

#define RES   256
#define RANK  12
#define NOUT  8
#define NPLANE (RES * RES)   // 65536 texels per plane

// ---------------------------------------------------------------------------
// FMA a weighted float4 into an accumulator, componentwise.
#define FMA4(acc, wgt, val)                                                    \
    do {                                                                       \
        (acc).x = fmaf((wgt), (val).x, (acc).x);                               \
        (acc).y = fmaf((wgt), (val).y, (acc).y);                               \
        (acc).z = fmaf((wgt), (val).z, (acc).z);                               \
        (acc).w = fmaf((wgt), (val).w, (acc).w);                               \
    } while (0)

// ---------------------------------------------------------------------------
// Kernel 1: fold the 8x36 projection into the planes.
// P[p][t][k] = sum_r proj_w[k][p*12 + r] * plane_p[t][r]
// grid = 3*65536/256 = 768 blocks of 256 threads, one thread per (plane,texel).
__global__ __launch_bounds__(256) void project_planes_kernel(
    const float* __restrict__ pxy, const float* __restrict__ pxz,
    const float* __restrict__ pyz, const float* __restrict__ w,
    float* __restrict__ P)
{
    int tid = blockIdx.x * 256 + threadIdx.x;   // 0 .. 3*65536-1
    int p = tid >> 16;
    int t = tid & (NPLANE - 1);
    const float* plane = (p == 0) ? pxy : ((p == 1) ? pxz : pyz);

    // 12 contiguous floats = 48 B = 3x float4 (16B-aligned since 48 % 16 == 0)
    const float4* src = (const float4*)(plane + (size_t)t * RANK);
    float4 a = src[0], b = src[1], c = src[2];
    float v[RANK] = {a.x, a.y, a.z, a.w, b.x, b.y, b.z, b.w, c.x, c.y, c.z, c.w};

    float o[NOUT];
#pragma unroll
    for (int k = 0; k < NOUT; ++k) {
        const float* wr = w + k * (3 * RANK) + p * RANK;
        float s = 0.0f;
#pragma unroll
        for (int r = 0; r < RANK; ++r) s = fmaf(wr[r], v[r], s);
        o[k] = s;
    }
    float4* dst = (float4*)(P + (size_t)tid * NOUT);
    dst[0] = make_float4(o[0], o[1], o[2], o[3]);
    dst[1] = make_float4(o[4], o[5], o[6], o[7]);
}

// ---------------------------------------------------------------------------
// Bilinear sample (align_corners=False, border padding) of an 8-channel
// projected plane, accumulated into (a0, a1).
// u indexes W (x of grid_sample), v indexes H.
__device__ __forceinline__ void sample_plane_acc(
    const float4* __restrict__ p4, float u, float v, float4& a0, float4& a1)
{
    float ix = fminf(fmaxf((u + 1.0f) * (RES * 0.5f) - 0.5f, 0.0f), RES - 1.0f);
    float iy = fminf(fmaxf((v + 1.0f) * (RES * 0.5f) - 0.5f, 0.0f), RES - 1.0f);
    float fx = floorf(ix), fy = floorf(iy);
    float wx = ix - fx, wy = iy - fy;
    int x0 = (int)fx, y0 = (int)fy;
    int x1 = min(x0 + 1, RES - 1), y1 = min(y0 + 1, RES - 1);
    float w00 = (1.0f - wx) * (1.0f - wy);
    float w01 = wx * (1.0f - wy);
    float w10 = (1.0f - wx) * wy;
    float w11 = wx * wy;
    int r0 = y0 * RES, r1 = y1 * RES;
    // each texel = 8 floats = 2 float4
    int i00 = (r0 + x0) * 2, i01 = (r0 + x1) * 2;
    int i10 = (r1 + x0) * 2, i11 = (r1 + x1) * 2;
    float4 c00a = p4[i00], c00b = p4[i00 + 1];
    float4 c01a = p4[i01], c01b = p4[i01 + 1];
    float4 c10a = p4[i10], c10b = p4[i10 + 1];
    float4 c11a = p4[i11], c11b = p4[i11 + 1];
    FMA4(a0, w00, c00a); FMA4(a1, w00, c00b);
    FMA4(a0, w01, c01a); FMA4(a1, w01, c01b);
    FMA4(a0, w10, c10a); FMA4(a1, w10, c10b);
    FMA4(a0, w11, c11a); FMA4(a1, w11, c11b);
}

// ---------------------------------------------------------------------------
// Kernel 2: per-point gather from projected planes, sum, bias, clip, store.
__global__ __launch_bounds__(256) void triplane_gather_kernel(
    const float* __restrict__ coords, const float* __restrict__ P,
    const float* __restrict__ bias, float* __restrict__ out, int N)
{
    int i = blockIdx.x * 256 + threadIdx.x;
    if (i >= N) return;
    float x = coords[3 * i + 0];
    float y = coords[3 * i + 1];
    float z = coords[3 * i + 2];
    // reference clips coords to [-1,1]; the [0,RES-1] clamp in
    // sample_plane_acc subsumes that exactly.

    float4 a0 = make_float4(0.f, 0.f, 0.f, 0.f);
    float4 a1 = make_float4(0.f, 0.f, 0.f, 0.f);
    const float4* P4 = (const float4*)P;
    sample_plane_acc(P4,                  x, y, a0, a1);  // plane_xy: (x->W, y->H)
    sample_plane_acc(P4 + NPLANE * 2,     x, z, a0, a1);  // plane_xz: (x->W, z->H)
    sample_plane_acc(P4 + 2 * NPLANE * 2, y, z, a0, a1);  // plane_yz: (y->W, z->H)

    const float4* b4 = (const float4*)bias;
    float4 bb0 = b4[0], bb1 = b4[1];
    a0.x += bb0.x; a0.y += bb0.y; a0.z += bb0.z; a0.w += bb0.w;
    a1.x += bb1.x; a1.y += bb1.y; a1.z += bb1.z; a1.w += bb1.w;
    a0.x = fminf(fmaxf(a0.x, -10.f), 10.f);
    a0.y = fminf(fmaxf(a0.y, -10.f), 10.f);
    a0.z = fminf(fmaxf(a0.z, -10.f), 10.f);
    a0.w = fminf(fmaxf(a0.w, -10.f), 10.f);
    a1.x = fminf(fmaxf(a1.x, -10.f), 10.f);
    a1.y = fminf(fmaxf(a1.y, -10.f), 10.f);
    a1.z = fminf(fmaxf(a1.z, -10.f), 10.f);
    a1.w = fminf(fmaxf(a1.w, -10.f), 10.f);

    float4* o4 = (float4*)(out + (size_t)i * NOUT);
    o4[0] = a0;
    o4[1] = a1;
}

// ---------------------------------------------------------------------------
// Fallback (only if ws_size can't hold the 6.3 MB projected planes):
// direct 12-channel sampling + in-thread 36x8 matvec.
__device__ __forceinline__ void sample12(const float* __restrict__ plane,
                                         float u, float v, float* __restrict__ f)
{
    float ix = fminf(fmaxf((u + 1.0f) * (RES * 0.5f) - 0.5f, 0.0f), RES - 1.0f);
    float iy = fminf(fmaxf((v + 1.0f) * (RES * 0.5f) - 0.5f, 0.0f), RES - 1.0f);
    float fx = floorf(ix), fy = floorf(iy);
    float wx = ix - fx, wy = iy - fy;
    int x0 = (int)fx, y0 = (int)fy;
    int x1 = min(x0 + 1, RES - 1), y1 = min(y0 + 1, RES - 1);
    float w00 = (1.0f - wx) * (1.0f - wy);
    float w01 = wx * (1.0f - wy);
    float w10 = (1.0f - wx) * wy;
    float w11 = wx * wy;
    const float4* p4 = (const float4*)plane;
    int i00 = (y0 * RES + x0) * 3, i01 = (y0 * RES + x1) * 3;
    int i10 = (y1 * RES + x0) * 3, i11 = (y1 * RES + x1) * 3;
#pragma unroll
    for (int j = 0; j < 3; ++j) {
        float4 c00 = p4[i00 + j], c01 = p4[i01 + j];
        float4 c10 = p4[i10 + j], c11 = p4[i11 + j];
        f[4 * j + 0] = fmaf(w00, c00.x, fmaf(w01, c01.x, fmaf(w10, c10.x, w11 * c11.x)));
        f[4 * j + 1] = fmaf(w00, c00.y, fmaf(w01, c01.y, fmaf(w10, c10.y, w11 * c11.y)));
        f[4 * j + 2] = fmaf(w00, c00.z, fmaf(w01, c01.z, fmaf(w10, c10.z, w11 * c11.z)));
        f[4 * j + 3] = fmaf(w00, c00.w, fmaf(w01, c01.w, fmaf(w10, c10.w, w11 * c11.w)));
    }
}

__global__ __launch_bounds__(256) void triplane_direct_kernel(
    const float* __restrict__ coords,
    const float* __restrict__ pxy, const float* __restrict__ pxz,
    const float* __restrict__ pyz,
    const float* __restrict__ w, const float* __restrict__ bias,
    float* __restrict__ out, int N)
{
    int i = blockIdx.x * 256 + threadIdx.x;
    if (i >= N) return;
    float x = coords[3 * i + 0];
    float y = coords[3 * i + 1];
    float z = coords[3 * i + 2];
    float f[3 * RANK];
    sample12(pxy, x, y, f + 0);
    sample12(pxz, x, z, f + RANK);
    sample12(pyz, y, z, f + 2 * RANK);
    float o[NOUT];
#pragma unroll
    for (int k = 0; k < NOUT; ++k) {
        const float* wr = w + k * (3 * RANK);
        float s = bias[k];
#pragma unroll
        for (int j = 0; j < 3 * RANK; ++j) s = fmaf(wr[j], f[j], s);
        o[k] = fminf(fmaxf(s, -10.f), 10.f);
    }
    float4* o4 = (float4*)(out + (size_t)i * NOUT);
    o4[0] = make_float4(o[0], o[1], o[2], o[3]);
    o4[1] = make_float4(o[4], o[5], o[6], o[7]);
}

// ---------------------------------------------------------------------------
extern "C" void kernel_launch(void* const* d_in, const int* in_sizes, int n_in,
                              void* d_out, int out_size, void* d_ws, size_t ws_size,
                              hipStream_t stream)
{
    const float* coords = (const float*)d_in[0];
    const float* pxy    = (const float*)d_in[1];
    const float* pxz    = (const float*)d_in[2];
    const float* pyz    = (const float*)d_in[3];
    const float* w      = (const float*)d_in[4];
    const float* b      = (const float*)d_in[5];
    float* out = (float*)d_out;
    int N = in_sizes[0] / 3;
    int blocks = (N + 255) / 256;

    size_t needP = (size_t)3 * NPLANE * NOUT * sizeof(float);  // 6,291,456 B
    if (ws_size >= needP) {
        float* P = (float*)d_ws;
        project_planes_kernel<<<(3 * NPLANE) / 256, 256, 0, stream>>>(pxy, pxz, pyz, w, P);
        triplane_gather_kernel<<<blocks, 256, 0, stream>>>(coords, P, b, out, N);
    } else {
        triplane_direct_kernel<<<blocks, 256, 0, stream>>>(coords, pxy, pxz, pyz, w, b, out, N);
    }
}

// Round 2
// 172.560 us; speedup vs baseline: 1.4929x; 1.4929x over previous
//
#include <hip/hip_runtime.h>

#define RES   256
#define RANK  12
#define NOUT  8
#define NPLANE (RES * RES)   // 65536 texels per plane

typedef _Float16 half8 __attribute__((ext_vector_type(8)));
typedef float    f32x4 __attribute__((ext_vector_type(4)));

// ---------------------------------------------------------------------------
// Kernel 1: fold the 8x36 projection into the planes, pack to fp16.
// P[p][t][k] = sum_r proj_w[k][p*12 + r] * plane_p[t][r]
// Values ~N(0, 3.5e-4): fp16 abs err <= ~1e-6, far under the 5.25e-5 budget.
__global__ __launch_bounds__(256) void project_planes_kernel(
    const float* __restrict__ pxy, const float* __restrict__ pxz,
    const float* __restrict__ pyz, const float* __restrict__ w,
    half8* __restrict__ P)
{
    int tid = blockIdx.x * 256 + threadIdx.x;   // 0 .. 3*65536-1
    int p = tid >> 16;
    int t = tid & (NPLANE - 1);
    const float* plane = (p == 0) ? pxy : ((p == 1) ? pxz : pyz);

    // 12 contiguous floats = 48 B = 3x float4 (16B-aligned since 48 % 16 == 0)
    const float4* src = (const float4*)(plane + (size_t)t * RANK);
    float4 a = src[0], b = src[1], c = src[2];
    float v[RANK] = {a.x, a.y, a.z, a.w, b.x, b.y, b.z, b.w, c.x, c.y, c.z, c.w};

    half8 h;
#pragma unroll
    for (int k = 0; k < NOUT; ++k) {
        const float* wr = w + k * (3 * RANK) + p * RANK;
        float s = 0.0f;
#pragma unroll
        for (int r = 0; r < RANK; ++r) s = fmaf(wr[r], v[r], s);
        h[k] = (_Float16)s;
    }
    P[tid] = h;
}

// ---------------------------------------------------------------------------
// Bilinear sample (align_corners=False, border padding) of an 8-channel
// fp16-packed projected plane, accumulated into acc[8].
// u indexes W (x of grid_sample), v indexes H. One 16-B load per corner.
__device__ __forceinline__ void sample_plane_acc(
    const half8* __restrict__ p8, float u, float v, float* __restrict__ acc)
{
    float ix = fminf(fmaxf((u + 1.0f) * (RES * 0.5f) - 0.5f, 0.0f), RES - 1.0f);
    float iy = fminf(fmaxf((v + 1.0f) * (RES * 0.5f) - 0.5f, 0.0f), RES - 1.0f);
    float fx = floorf(ix), fy = floorf(iy);
    float wx = ix - fx, wy = iy - fy;
    int x0 = (int)fx, y0 = (int)fy;
    int x1 = min(x0 + 1, RES - 1), y1 = min(y0 + 1, RES - 1);
    float w00 = (1.0f - wx) * (1.0f - wy);
    float w01 = wx * (1.0f - wy);
    float w10 = (1.0f - wx) * wy;
    float w11 = wx * wy;
    int r0 = y0 * RES, r1 = y1 * RES;
    half8 c00 = p8[r0 + x0];
    half8 c01 = p8[r0 + x1];
    half8 c10 = p8[r1 + x0];
    half8 c11 = p8[r1 + x1];
#pragma unroll
    for (int k = 0; k < NOUT; ++k) {
        float s = acc[k];
        s = fmaf(w00, (float)c00[k], s);
        s = fmaf(w01, (float)c01[k], s);
        s = fmaf(w10, (float)c10[k], s);
        s = fmaf(w11, (float)c11[k], s);
        acc[k] = s;
    }
}

// ---------------------------------------------------------------------------
// Kernel 2: per-point gather from fp16 projected planes, sum, bias, clip, store.
// Nontemporal coord loads / output stores keep the streaming 88 MB out of L2
// so the 3.0 MB plane set stays resident (4 MB L2 per XCD).
__global__ __launch_bounds__(256) void triplane_gather_kernel(
    const float* __restrict__ coords, const half8* __restrict__ P,
    const float* __restrict__ bias, float* __restrict__ out, int N)
{
    int i = blockIdx.x * 256 + threadIdx.x;
    if (i >= N) return;
    float x = __builtin_nontemporal_load(coords + 3 * i + 0);
    float y = __builtin_nontemporal_load(coords + 3 * i + 1);
    float z = __builtin_nontemporal_load(coords + 3 * i + 2);
    // reference clips coords to [-1,1]; the [0,RES-1] clamp in
    // sample_plane_acc subsumes that exactly.

    float acc[NOUT];
#pragma unroll
    for (int k = 0; k < NOUT; ++k) acc[k] = bias[k];

    sample_plane_acc(P,              x, y, acc);  // plane_xy: (x->W, y->H)
    sample_plane_acc(P + NPLANE,     x, z, acc);  // plane_xz: (x->W, z->H)
    sample_plane_acc(P + 2 * NPLANE, y, z, acc);  // plane_yz: (y->W, z->H)

    f32x4 o0, o1;
#pragma unroll
    for (int k = 0; k < 4; ++k) o0[k] = fminf(fmaxf(acc[k],     -10.f), 10.f);
#pragma unroll
    for (int k = 0; k < 4; ++k) o1[k] = fminf(fmaxf(acc[4 + k], -10.f), 10.f);

    f32x4* o4 = (f32x4*)(out + (size_t)i * NOUT);
    __builtin_nontemporal_store(o0, o4);
    __builtin_nontemporal_store(o1, o4 + 1);
}

// ---------------------------------------------------------------------------
// Fallback (only if ws_size can't hold the 3.0 MB projected planes):
// direct 12-channel fp32 sampling + in-thread 36x8 matvec.
__device__ __forceinline__ void sample12(const float* __restrict__ plane,
                                         float u, float v, float* __restrict__ f)
{
    float ix = fminf(fmaxf((u + 1.0f) * (RES * 0.5f) - 0.5f, 0.0f), RES - 1.0f);
    float iy = fminf(fmaxf((v + 1.0f) * (RES * 0.5f) - 0.5f, 0.0f), RES - 1.0f);
    float fx = floorf(ix), fy = floorf(iy);
    float wx = ix - fx, wy = iy - fy;
    int x0 = (int)fx, y0 = (int)fy;
    int x1 = min(x0 + 1, RES - 1), y1 = min(y0 + 1, RES - 1);
    float w00 = (1.0f - wx) * (1.0f - wy);
    float w01 = wx * (1.0f - wy);
    float w10 = (1.0f - wx) * wy;
    float w11 = wx * wy;
    const float4* p4 = (const float4*)plane;
    int i00 = (y0 * RES + x0) * 3, i01 = (y0 * RES + x1) * 3;
    int i10 = (y1 * RES + x0) * 3, i11 = (y1 * RES + x1) * 3;
#pragma unroll
    for (int j = 0; j < 3; ++j) {
        float4 c00 = p4[i00 + j], c01 = p4[i01 + j];
        float4 c10 = p4[i10 + j], c11 = p4[i11 + j];
        f[4 * j + 0] = fmaf(w00, c00.x, fmaf(w01, c01.x, fmaf(w10, c10.x, w11 * c11.x)));
        f[4 * j + 1] = fmaf(w00, c00.y, fmaf(w01, c01.y, fmaf(w10, c10.y, w11 * c11.y)));
        f[4 * j + 2] = fmaf(w00, c00.z, fmaf(w01, c01.z, fmaf(w10, c10.z, w11 * c11.z)));
        f[4 * j + 3] = fmaf(w00, c00.w, fmaf(w01, c01.w, fmaf(w10, c10.w, w11 * c11.w)));
    }
}

__global__ __launch_bounds__(256) void triplane_direct_kernel(
    const float* __restrict__ coords,
    const float* __restrict__ pxy, const float* __restrict__ pxz,
    const float* __restrict__ pyz,
    const float* __restrict__ w, const float* __restrict__ bias,
    float* __restrict__ out, int N)
{
    int i = blockIdx.x * 256 + threadIdx.x;
    if (i >= N) return;
    float x = coords[3 * i + 0];
    float y = coords[3 * i + 1];
    float z = coords[3 * i + 2];
    float f[3 * RANK];
    sample12(pxy, x, y, f + 0);
    sample12(pxz, x, z, f + RANK);
    sample12(pyz, y, z, f + 2 * RANK);
    float o[NOUT];
#pragma unroll
    for (int k = 0; k < NOUT; ++k) {
        const float* wr = w + k * (3 * RANK);
        float s = bias[k];
#pragma unroll
        for (int j = 0; j < 3 * RANK; ++j) s = fmaf(wr[j], f[j], s);
        o[k] = fminf(fmaxf(s, -10.f), 10.f);
    }
    float4* o4 = (float4*)(out + (size_t)i * NOUT);
    o4[0] = make_float4(o[0], o[1], o[2], o[3]);
    o4[1] = make_float4(o[4], o[5], o[6], o[7]);
}

// ---------------------------------------------------------------------------
extern "C" void kernel_launch(void* const* d_in, const int* in_sizes, int n_in,
                              void* d_out, int out_size, void* d_ws, size_t ws_size,
                              hipStream_t stream)
{
    const float* coords = (const float*)d_in[0];
    const float* pxy    = (const float*)d_in[1];
    const float* pxz    = (const float*)d_in[2];
    const float* pyz    = (const float*)d_in[3];
    const float* w      = (const float*)d_in[4];
    const float* b      = (const float*)d_in[5];
    float* out = (float*)d_out;
    int N = in_sizes[0] / 3;
    int blocks = (N + 255) / 256;

    size_t needP = (size_t)3 * NPLANE * NOUT * sizeof(_Float16);  // 3,145,728 B
    if (ws_size >= needP) {
        half8* P = (half8*)d_ws;
        project_planes_kernel<<<(3 * NPLANE) / 256, 256, 0, stream>>>(pxy, pxz, pyz, w, P);
        triplane_gather_kernel<<<blocks, 256, 0, stream>>>(coords, P, b, out, N);
    } else {
        triplane_direct_kernel<<<blocks, 256, 0, stream>>>(coords, pxy, pxz, pyz, w, b, out, N);
    }
}

// Round 3
// 163.187 us; speedup vs baseline: 1.5786x; 1.0574x over previous
//
#include <hip/hip_runtime.h>

#define RES   256
#define RANK  12
#define NOUT  8
#define NPLANE (RES * RES)   // 65536 texels per plane

typedef _Float16 half8 __attribute__((ext_vector_type(8)));
typedef float    f32x2 __attribute__((ext_vector_type(2)));

// ---------------------------------------------------------------------------
// Kernel 1: fold the 8x36 projection into the planes, pack to fp16.
// P[p][t][k] = sum_r proj_w[k][p*12 + r] * plane_p[t][r]
// Values ~N(0, 3.5e-4): fp16 abs err <= ~1e-6, far under the 5.25e-5 budget.
__global__ __launch_bounds__(256) void project_planes_kernel(
    const float* __restrict__ pxy, const float* __restrict__ pxz,
    const float* __restrict__ pyz, const float* __restrict__ w,
    half8* __restrict__ P)
{
    int tid = blockIdx.x * 256 + threadIdx.x;   // 0 .. 3*65536-1
    int p = tid >> 16;
    int t = tid & (NPLANE - 1);
    const float* plane = (p == 0) ? pxy : ((p == 1) ? pxz : pyz);

    // 12 contiguous floats = 48 B = 3x float4 (16B-aligned since 48 % 16 == 0)
    const float4* src = (const float4*)(plane + (size_t)t * RANK);
    float4 a = src[0], b = src[1], c = src[2];
    float v[RANK] = {a.x, a.y, a.z, a.w, b.x, b.y, b.z, b.w, c.x, c.y, c.z, c.w};

    half8 h;
#pragma unroll
    for (int k = 0; k < NOUT; ++k) {
        const float* wr = w + k * (3 * RANK) + p * RANK;
        float s = 0.0f;
#pragma unroll
        for (int r = 0; r < RANK; ++r) s = fmaf(wr[r], v[r], s);
        h[k] = (_Float16)s;
    }
    P[tid] = h;
}

// ---------------------------------------------------------------------------
// Compute this lane's bilinear corner (texel index within one plane + weight).
// u indexes W, v indexes H; c in [0,4): bit0 = x-side, bit1 = y-side.
// align_corners=False, border padding — matches the reference exactly
// (coords pre-clip to [-1,1] is subsumed by the [0, RES-1] clamp).
__device__ __forceinline__ void corner_addr(float u, float v, int c,
                                            int& idx, float& wc)
{
    float ix = fminf(fmaxf((u + 1.0f) * (RES * 0.5f) - 0.5f, 0.0f), RES - 1.0f);
    float iy = fminf(fmaxf((v + 1.0f) * (RES * 0.5f) - 0.5f, 0.0f), RES - 1.0f);
    float fx = floorf(ix), fy = floorf(iy);
    float wx = ix - fx, wy = iy - fy;
    int x0 = (int)fx, y0 = (int)fy;
    int xs = c & 1;
    int ys = (c >> 1) & 1;
    int cx = min(x0 + xs, RES - 1);
    int cy = min(y0 + ys, RES - 1);
    wc = (xs ? wx : 1.0f - wx) * (ys ? wy : 1.0f - wy);
    idx = (cy << 8) | cx;
}

// ---------------------------------------------------------------------------
// Kernel 2: 4 lanes per point, one bilinear corner per lane.
// Adjacent lanes fetch adjacent texels -> same 64B L2 line 75% of the time,
// cutting L2->L1 line traffic ~1.6x vs one-point-per-lane. Quad butterfly
// (shfl_xor 1,2) sums the 4 weighted corners; each lane stores 2 of the 8
// output channels -> perfectly coalesced 512 B/wave stores.
__global__ __launch_bounds__(256) void triplane_gather_quad_kernel(
    const float* __restrict__ coords, const half8* __restrict__ P,
    const float* __restrict__ bias, float* __restrict__ out, int N)
{
    int g = blockIdx.x * 256 + threadIdx.x;
    int p = g >> 2;          // point index
    int c = g & 3;           // corner index
    if (p >= N) return;

    float x = __builtin_nontemporal_load(coords + 3 * p + 0);
    float y = __builtin_nontemporal_load(coords + 3 * p + 1);
    float z = __builtin_nontemporal_load(coords + 3 * p + 2);

    int i0, i1, i2;
    float w0, w1, w2;
    corner_addr(x, y, c, i0, w0);   // plane_xy: (x->W, y->H)
    corner_addr(x, z, c, i1, w1);   // plane_xz: (x->W, z->H)
    corner_addr(y, z, c, i2, w2);   // plane_yz: (y->W, z->H)

    half8 t0 = P[i0];
    half8 t1 = P[NPLANE + i1];
    half8 t2 = P[2 * NPLANE + i2];

    float acc[NOUT];
#pragma unroll
    for (int k = 0; k < NOUT; ++k)
        acc[k] = fmaf(w0, (float)t0[k],
                 fmaf(w1, (float)t1[k], w2 * (float)t2[k]));

    // sum the 4 corner-lanes of the quad (result valid in all 4 lanes)
#pragma unroll
    for (int k = 0; k < NOUT; ++k) {
        acc[k] += __shfl_xor(acc[k], 1);
        acc[k] += __shfl_xor(acc[k], 2);
    }

    f32x2 o;
    o.x = fminf(fmaxf(acc[2 * c]     + bias[2 * c],     -10.f), 10.f);
    o.y = fminf(fmaxf(acc[2 * c + 1] + bias[2 * c + 1], -10.f), 10.f);
    __builtin_nontemporal_store(o, (f32x2*)out + g);   // out[2g .. 2g+1]
}

// ---------------------------------------------------------------------------
// Fallback (only if ws_size can't hold the 3.0 MB projected planes):
// direct 12-channel fp32 sampling + in-thread 36x8 matvec.
__device__ __forceinline__ void sample12(const float* __restrict__ plane,
                                         float u, float v, float* __restrict__ f)
{
    float ix = fminf(fmaxf((u + 1.0f) * (RES * 0.5f) - 0.5f, 0.0f), RES - 1.0f);
    float iy = fminf(fmaxf((v + 1.0f) * (RES * 0.5f) - 0.5f, 0.0f), RES - 1.0f);
    float fx = floorf(ix), fy = floorf(iy);
    float wx = ix - fx, wy = iy - fy;
    int x0 = (int)fx, y0 = (int)fy;
    int x1 = min(x0 + 1, RES - 1), y1 = min(y0 + 1, RES - 1);
    float w00 = (1.0f - wx) * (1.0f - wy);
    float w01 = wx * (1.0f - wy);
    float w10 = (1.0f - wx) * wy;
    float w11 = wx * wy;
    const float4* p4 = (const float4*)plane;
    int i00 = (y0 * RES + x0) * 3, i01 = (y0 * RES + x1) * 3;
    int i10 = (y1 * RES + x0) * 3, i11 = (y1 * RES + x1) * 3;
#pragma unroll
    for (int j = 0; j < 3; ++j) {
        float4 c00 = p4[i00 + j], c01 = p4[i01 + j];
        float4 c10 = p4[i10 + j], c11 = p4[i11 + j];
        f[4 * j + 0] = fmaf(w00, c00.x, fmaf(w01, c01.x, fmaf(w10, c10.x, w11 * c11.x)));
        f[4 * j + 1] = fmaf(w00, c00.y, fmaf(w01, c01.y, fmaf(w10, c10.y, w11 * c11.y)));
        f[4 * j + 2] = fmaf(w00, c00.z, fmaf(w01, c01.z, fmaf(w10, c10.z, w11 * c11.z)));
        f[4 * j + 3] = fmaf(w00, c00.w, fmaf(w01, c01.w, fmaf(w10, c10.w, w11 * c11.w)));
    }
}

__global__ __launch_bounds__(256) void triplane_direct_kernel(
    const float* __restrict__ coords,
    const float* __restrict__ pxy, const float* __restrict__ pxz,
    const float* __restrict__ pyz,
    const float* __restrict__ w, const float* __restrict__ bias,
    float* __restrict__ out, int N)
{
    int i = blockIdx.x * 256 + threadIdx.x;
    if (i >= N) return;
    float x = coords[3 * i + 0];
    float y = coords[3 * i + 1];
    float z = coords[3 * i + 2];
    float f[3 * RANK];
    sample12(pxy, x, y, f + 0);
    sample12(pxz, x, z, f + RANK);
    sample12(pyz, y, z, f + 2 * RANK);
    float o[NOUT];
#pragma unroll
    for (int k = 0; k < NOUT; ++k) {
        const float* wr = w + k * (3 * RANK);
        float s = bias[k];
#pragma unroll
        for (int j = 0; j < 3 * RANK; ++j) s = fmaf(wr[j], f[j], s);
        o[k] = fminf(fmaxf(s, -10.f), 10.f);
    }
    float4* o4 = (float4*)(out + (size_t)i * NOUT);
    o4[0] = make_float4(o[0], o[1], o[2], o[3]);
    o4[1] = make_float4(o[4], o[5], o[6], o[7]);
}

// ---------------------------------------------------------------------------
extern "C" void kernel_launch(void* const* d_in, const int* in_sizes, int n_in,
                              void* d_out, int out_size, void* d_ws, size_t ws_size,
                              hipStream_t stream)
{
    const float* coords = (const float*)d_in[0];
    const float* pxy    = (const float*)d_in[1];
    const float* pxz    = (const float*)d_in[2];
    const float* pyz    = (const float*)d_in[3];
    const float* w      = (const float*)d_in[4];
    const float* b      = (const float*)d_in[5];
    float* out = (float*)d_out;
    int N = in_sizes[0] / 3;

    size_t needP = (size_t)3 * NPLANE * NOUT * sizeof(_Float16);  // 3,145,728 B
    if (ws_size >= needP) {
        half8* P = (half8*)d_ws;
        project_planes_kernel<<<(3 * NPLANE) / 256, 256, 0, stream>>>(pxy, pxz, pyz, w, P);
        long long threads = 4LL * N;
        int blocks = (int)((threads + 255) / 256);
        triplane_gather_quad_kernel<<<blocks, 256, 0, stream>>>(coords, P, b, out, N);
    } else {
        int blocks = (N + 255) / 256;
        triplane_direct_kernel<<<blocks, 256, 0, stream>>>(coords, pxy, pxz, pyz, w, b, out, N);
    }
}

// Round 5
// 155.252 us; speedup vs baseline: 1.6593x; 1.0511x over previous
//
#include <hip/hip_runtime.h>

#define RES   256
#define RANK  12
#define NOUT  8
#define NPLANE (RES * RES)   // 65536 texels per plane

typedef _Float16 half8 __attribute__((ext_vector_type(8)));
typedef _Float16 h2    __attribute__((ext_vector_type(2)));
typedef int      i32x4 __attribute__((ext_vector_type(4)));
typedef float    f32x4 __attribute__((ext_vector_type(4)));

// ---------------------------------------------------------------------------
// Kernel 1: fold the 8x36 projection into the planes, pack to fp16.
// P[p][t][k] = sum_r proj_w[k][p*12 + r] * plane_p[t][r]
// Values ~N(0, 3.5e-4): fp16 texel quant err ~1e-6, well under budget.
__global__ __launch_bounds__(256) void project_planes_kernel(
    const float* __restrict__ pxy, const float* __restrict__ pxz,
    const float* __restrict__ pyz, const float* __restrict__ w,
    half8* __restrict__ P)
{
    int tid = blockIdx.x * 256 + threadIdx.x;   // 0 .. 3*65536-1
    int p = tid >> 16;
    int t = tid & (NPLANE - 1);
    const float* plane = (p == 0) ? pxy : ((p == 1) ? pxz : pyz);

    const float4* src = (const float4*)(plane + (size_t)t * RANK);
    float4 a = src[0], b = src[1], c = src[2];
    float v[RANK] = {a.x, a.y, a.z, a.w, b.x, b.y, b.z, b.w, c.x, c.y, c.z, c.w};

    half8 h;
#pragma unroll
    for (int k = 0; k < NOUT; ++k) {
        const float* wr = w + k * (3 * RANK) + p * RANK;
        float s = 0.0f;
#pragma unroll
        for (int r = 0; r < RANK; ++r) s = fmaf(wr[r], v[r], s);
        h[k] = (_Float16)s;
    }
    P[tid] = h;
}

// ---------------------------------------------------------------------------
// Unnormalize one grid_sample coordinate (align_corners=False, border clamp).
// ic = clamp((c+1)*128 - 0.5, 0, 255) = clamp(fma(c,128,127.5), 0, 255)
__device__ __forceinline__ void unnorm(float c, int& i0, float& fr)
{
    float ic = fminf(fmaxf(fmaf(c, 128.0f, 127.5f), 0.0f), (float)(RES - 1));
    float f = floorf(ic);
    fr = ic - f;
    i0 = (int)f;
}

// ---------------------------------------------------------------------------
// One plane's contribution for this lane's column side (xs in {0,1}).
// Loads the two row texels of column cx and accumulates w*texel in packed fp16.
__device__ __forceinline__ void sample_col(
    const half8* __restrict__ base, int wi, float wf, int hi, float hf,
    int xs, half8& acc)
{
    int cx = min(wi + xs, RES - 1);
    float wx = xs ? wf : (1.0f - wf);
    int r0 = hi << 8;
    int r1 = min(hi + 1, RES - 1) << 8;
    half8 t0 = base[r0 + cx];
    half8 t1 = base[r1 + cx];
    _Float16 wa = (_Float16)(wx * (1.0f - hf));
    _Float16 wb = (_Float16)(wx * hf);
    acc += t0 * wa + t1 * wb;   // 8x v_pk_fma_f16
}

// ---------------------------------------------------------------------------
// Kernel 2: 2 lanes per point, split by bilinear column (x0 vs x1).
// Adjacent lanes fetch x-adjacent texels -> same 64B line 75% of the time
// (all the coalescing the quad scheme had, at half the threads). Coordinate
// unnormalization shared across the 3 planes. Texel weighting/accumulation
// in packed fp16 (v_pk_fma_f16, 4x fewer VALU ops than cvt+fp32-fma).
// One shfl_xor(1) combines the column pair; lane xs stores channels
// 4xs..4xs+3 -> ((f32x4*)out)[g] is perfectly coalesced 1 KB/wave.
__global__ __launch_bounds__(256) void triplane_gather_pair_kernel(
    const float* __restrict__ coords, const half8* __restrict__ P,
    const float* __restrict__ bias, float* __restrict__ out, int N)
{
    int g = blockIdx.x * 256 + threadIdx.x;
    int p = g >> 1;          // point index
    int xs = g & 1;          // column side
    if (p >= N) return;

    float x = __builtin_nontemporal_load(coords + 3 * p + 0);
    float y = __builtin_nontemporal_load(coords + 3 * p + 1);
    float z = __builtin_nontemporal_load(coords + 3 * p + 2);
    // reference pre-clip to [-1,1] is subsumed by unnorm's [0,255] clamp.

    int xi, yi, zi;
    float xf, yf, zf;
    unnorm(x, xi, xf);
    unnorm(y, yi, yf);
    unnorm(z, zi, zf);

    half8 acc = {};
    sample_col(P,              xi, xf, yi, yf, xs, acc);  // plane_xy: x->W, y->H
    sample_col(P + NPLANE,     xi, xf, zi, zf, xs, acc);  // plane_xz: x->W, z->H
    sample_col(P + 2 * NPLANE, yi, yf, zi, zf, xs, acc);  // plane_yz: y->W, z->H

    // add partner lane's accumulator (other column side)
    i32x4 ai = __builtin_bit_cast(i32x4, acc);
    i32x4 bi;
    bi[0] = __shfl_xor(ai[0], 1);
    bi[1] = __shfl_xor(ai[1], 1);
    bi[2] = __shfl_xor(ai[2], 1);
    bi[3] = __shfl_xor(ai[3], 1);
    acc += __builtin_bit_cast(half8, bi);

    // lane xs outputs channels 4xs..4xs+3
    i32x4 s = __builtin_bit_cast(i32x4, acc);
    int u0 = xs ? s[2] : s[0];
    int u1 = xs ? s[3] : s[1];
    h2 c01 = __builtin_bit_cast(h2, u0);
    h2 c23 = __builtin_bit_cast(h2, u1);

    const f32x4* b4 = (const f32x4*)bias;
    f32x4 bb = b4[xs];
    f32x4 r;
    r.x = fminf(fmaxf((float)c01[0] + bb.x, -10.f), 10.f);
    r.y = fminf(fmaxf((float)c01[1] + bb.y, -10.f), 10.f);
    r.z = fminf(fmaxf((float)c23[0] + bb.z, -10.f), 10.f);
    r.w = fminf(fmaxf((float)c23[1] + bb.w, -10.f), 10.f);

    __builtin_nontemporal_store(r, (f32x4*)out + g);   // out[8p + 4xs ...]
}

// ---------------------------------------------------------------------------
// Fallback (only if ws_size can't hold the 3.0 MB projected planes):
// direct 12-channel fp32 sampling + in-thread 36x8 matvec.
__device__ __forceinline__ void sample12(const float* __restrict__ plane,
                                         float u, float v, float* __restrict__ f)
{
    float ix = fminf(fmaxf((u + 1.0f) * (RES * 0.5f) - 0.5f, 0.0f), RES - 1.0f);
    float iy = fminf(fmaxf((v + 1.0f) * (RES * 0.5f) - 0.5f, 0.0f), RES - 1.0f);
    float fx = floorf(ix), fy = floorf(iy);
    float wx = ix - fx, wy = iy - fy;
    int x0 = (int)fx, y0 = (int)fy;
    int x1 = min(x0 + 1, RES - 1), y1 = min(y0 + 1, RES - 1);
    float w00 = (1.0f - wx) * (1.0f - wy);
    float w01 = wx * (1.0f - wy);
    float w10 = (1.0f - wx) * wy;
    float w11 = wx * wy;
    const float4* p4 = (const float4*)plane;
    int i00 = (y0 * RES + x0) * 3, i01 = (y0 * RES + x1) * 3;
    int i10 = (y1 * RES + x0) * 3, i11 = (y1 * RES + x1) * 3;
#pragma unroll
    for (int j = 0; j < 3; ++j) {
        float4 c00 = p4[i00 + j], c01 = p4[i01 + j];
        float4 c10 = p4[i10 + j], c11 = p4[i11 + j];
        f[4 * j + 0] = fmaf(w00, c00.x, fmaf(w01, c01.x, fmaf(w10, c10.x, w11 * c11.x)));
        f[4 * j + 1] = fmaf(w00, c00.y, fmaf(w01, c01.y, fmaf(w10, c10.y, w11 * c11.y)));
        f[4 * j + 2] = fmaf(w00, c00.z, fmaf(w01, c01.z, fmaf(w10, c10.z, w11 * c11.z)));
        f[4 * j + 3] = fmaf(w00, c00.w, fmaf(w01, c01.w, fmaf(w10, c10.w, w11 * c11.w)));
    }
}

__global__ __launch_bounds__(256) void triplane_direct_kernel(
    const float* __restrict__ coords,
    const float* __restrict__ pxy, const float* __restrict__ pxz,
    const float* __restrict__ pyz,
    const float* __restrict__ w, const float* __restrict__ bias,
    float* __restrict__ out, int N)
{
    int i = blockIdx.x * 256 + threadIdx.x;
    if (i >= N) return;
    float x = coords[3 * i + 0];
    float y = coords[3 * i + 1];
    float z = coords[3 * i + 2];
    float f[3 * RANK];
    sample12(pxy, x, y, f + 0);
    sample12(pxz, x, z, f + RANK);
    sample12(pyz, y, z, f + 2 * RANK);
    float o[NOUT];
#pragma unroll
    for (int k = 0; k < NOUT; ++k) {
        const float* wr = w + k * (3 * RANK);
        float s = bias[k];
#pragma unroll
        for (int j = 0; j < 3 * RANK; ++j) s = fmaf(wr[j], f[j], s);
        o[k] = fminf(fmaxf(s, -10.f), 10.f);
    }
    float4* o4 = (float4*)(out + (size_t)i * NOUT);
    o4[0] = make_float4(o[0], o[1], o[2], o[3]);
    o4[1] = make_float4(o[4], o[5], o[6], o[7]);
}

// ---------------------------------------------------------------------------
extern "C" void kernel_launch(void* const* d_in, const int* in_sizes, int n_in,
                              void* d_out, int out_size, void* d_ws, size_t ws_size,
                              hipStream_t stream)
{
    const float* coords = (const float*)d_in[0];
    const float* pxy    = (const float*)d_in[1];
    const float* pxz    = (const float*)d_in[2];
    const float* pyz    = (const float*)d_in[3];
    const float* w      = (const float*)d_in[4];
    const float* b      = (const float*)d_in[5];
    float* out = (float*)d_out;
    int N = in_sizes[0] / 3;

    size_t needP = (size_t)3 * NPLANE * NOUT * sizeof(_Float16);  // 3,145,728 B
    if (ws_size >= needP) {
        half8* P = (half8*)d_ws;
        project_planes_kernel<<<(3 * NPLANE) / 256, 256, 0, stream>>>(pxy, pxz, pyz, w, P);
        long long threads = 2LL * N;
        int blocks = (int)((threads + 255) / 256);
        triplane_gather_pair_kernel<<<blocks, 256, 0, stream>>>(coords, P, b, out, N);
    } else {
        int blocks = (N + 255) / 256;
        triplane_direct_kernel<<<blocks, 256, 0, stream>>>(coords, pxy, pxz, pyz, w, b, out, N);
    }
}